// Round 2
// baseline (3273.651 us; speedup 1.0000x reference)
//
#include <hip/hip_runtime.h>

#define NN 50000
#define HH 128
#define EE 800000

// ---------------------------------------------------------------------------
// Kernel 1: BN(eval) + ReLU -> hn ; zero-init denom/num accumulators
// ---------------------------------------------------------------------------
__global__ __launch_bounds__(256) void init_kernel(
    const float* __restrict__ h,
    const float* __restrict__ bnw,
    const float* __restrict__ bnb,
    const float* __restrict__ bnm,
    const float* __restrict__ bnv,
    float* __restrict__ hn,
    float* __restrict__ denom,
    float* __restrict__ num)
{
    int i4 = blockIdx.x * 256 + threadIdx.x;      // N*H/4 threads exactly
    int c4 = i4 & 31;                              // 128/4 = 32 float4 per row
    const float4 wv = ((const float4*)bnw)[c4];
    const float4 bv = ((const float4*)bnb)[c4];
    const float4 mv = ((const float4*)bnm)[c4];
    const float4 vv = ((const float4*)bnv)[c4];
    const float4 xv = ((const float4*)h)[i4];
    float4 r;
    r.x = fmaxf((xv.x - mv.x) * rsqrtf(vv.x + 1e-5f) * wv.x + bv.x, 0.f);
    r.y = fmaxf((xv.y - mv.y) * rsqrtf(vv.y + 1e-5f) * wv.y + bv.y, 0.f);
    r.z = fmaxf((xv.z - mv.z) * rsqrtf(vv.z + 1e-5f) * wv.z + bv.z, 0.f);
    r.w = fmaxf((xv.w - mv.w) * rsqrtf(vv.w + 1e-5f) * wv.w + bv.w, 0.f);
    ((float4*)hn)[i4] = r;
    const float4 z4 = make_float4(0.f, 0.f, 0.f, 0.f);
    ((float4*)denom)[i4] = z4;
    ((float4*)num)[i4]   = z4;
}

// ---------------------------------------------------------------------------
// Kernel 2: single-pass softmax-aggregation accumulation.
//   msg = relu(hn[src]+ea)+1e-7 ; ex = exp(msg*t)   (no max-subtraction:
//   shift-invariant, logits bounded ~12 so f32 exp is safe)
//   denom[dst,c] += ex ; num[dst,c] += msg*ex
// 32 threads per edge, float4 per thread.
// ---------------------------------------------------------------------------
__global__ __launch_bounds__(256) void edge_kernel(
    const float* __restrict__ hn,
    const int*   __restrict__ ei,
    const float* __restrict__ ea,
    const float* __restrict__ tptr,
    float* __restrict__ denom,
    float* __restrict__ num)
{
    int gid = blockIdx.x * 256 + threadIdx.x;      // E*32 threads exactly
    int e = gid >> 5;
    int c = (gid & 31) << 2;
    int src = ei[e];
    int dst = ei[EE + e];
    float t = tptr[0];
    const float4 a  = *(const float4*)(ea + (size_t)e * HH + c);
    const float4 hs = *(const float4*)(hn + (size_t)src * HH + c);

    float m0 = fmaxf(hs.x + a.x, 0.f) + 1e-7f;
    float m1 = fmaxf(hs.y + a.y, 0.f) + 1e-7f;
    float m2 = fmaxf(hs.z + a.z, 0.f) + 1e-7f;
    float m3 = fmaxf(hs.w + a.w, 0.f) + 1e-7f;

    float e0 = __expf(m0 * t);
    float e1 = __expf(m1 * t);
    float e2 = __expf(m2 * t);
    float e3 = __expf(m3 * t);

    size_t ridx = (size_t)dst * HH + c;
    atomicAdd(denom + ridx + 0, e0);
    atomicAdd(denom + ridx + 1, e1);
    atomicAdd(denom + ridx + 2, e2);
    atomicAdd(denom + ridx + 3, e3);
    atomicAdd(num + ridx + 0, m0 * e0);
    atomicAdd(num + ridx + 1, m1 * e1);
    atomicAdd(num + ridx + 2, m2 * e2);
    atomicAdd(num + ridx + 3, m3 * e3);
}

// ---------------------------------------------------------------------------
// Kernel 3: per-node  out = num/denom + hn ; y = LN(out@W1+b1) relu ; 
//           final = h + (y@W2+b2).  8 nodes per 256-thread block.
// ---------------------------------------------------------------------------
__global__ __launch_bounds__(256) void mlp_kernel(
    const float* __restrict__ h,
    const float* __restrict__ hn,
    const float* __restrict__ denom,
    const float* __restrict__ num,
    const float* __restrict__ W1,
    const float* __restrict__ b1,
    const float* __restrict__ lnw,
    const float* __restrict__ lnb,
    const float* __restrict__ W2,
    const float* __restrict__ b2,
    float* __restrict__ out)
{
    __shared__ float s_out[8][128];
    __shared__ float s_y[8][256];
    __shared__ float s_mu[8], s_rs[8];

    const int tid = threadIdx.x;
    const int nb  = blockIdx.x * 8;                // N divisible by 8 (50000/8=6250)

    // Phase A: aggregated output + skip (x_r = hn)
    #pragma unroll
    for (int p = 0; p < 4; ++p) {
        int idx = tid + p * 256;                   // 0..1023
        int n = idx >> 7, k = idx & 127;
        size_t g = (size_t)(nb + n) * HH + k;
        s_out[n][k] = num[g] / (denom[g] + 1e-16f) + hn[g];
    }
    __syncthreads();

    // Phase B: y1[j] = out . W1[:,j] + b1[j]   (thread j owns column j, 8 nodes)
    float acc[8];
    {
        float bj = b1[tid];
        #pragma unroll
        for (int n = 0; n < 8; ++n) acc[n] = bj;
        for (int k = 0; k < 128; ++k) {
            float wv = W1[k * 256 + tid];
            #pragma unroll
            for (int n = 0; n < 8; ++n) acc[n] += s_out[n][k] * wv;
        }
        #pragma unroll
        for (int n = 0; n < 8; ++n) s_y[n][tid] = acc[n];
    }
    __syncthreads();

    // Phase C: LayerNorm stats — 8 groups of 32 lanes, one node each
    {
        int grp = tid >> 5, lane = tid & 31;
        float s = 0.f, sq = 0.f;
        for (int j = lane; j < 256; j += 32) {
            float v = s_y[grp][j];
            s += v; sq += v * v;
        }
        #pragma unroll
        for (int off = 16; off > 0; off >>= 1) {
            s  += __shfl_down(s,  off, 32);
            sq += __shfl_down(sq, off, 32);
        }
        if (lane == 0) {
            float mu  = s * (1.f / 256.f);
            float var = sq * (1.f / 256.f) - mu * mu;
            s_mu[grp] = mu;
            s_rs[grp] = rsqrtf(var + 1e-5f);
        }
    }
    __syncthreads();

    // Phase D: apply LN + ReLU
    {
        float lw = lnw[tid], lb = lnb[tid];
        #pragma unroll
        for (int n = 0; n < 8; ++n) {
            float v = (s_y[n][tid] - s_mu[n]) * s_rs[n] * lw + lb;
            s_y[n][tid] = fmaxf(v, 0.f);
        }
    }
    __syncthreads();

    // Phase E: z[j] = y . W2[:,j] + b2[j]; final = h + z
    // threads 0..127 -> nodes 0..3 ; threads 128..255 -> nodes 4..7
    {
        int j  = tid & 127;
        int n0 = (tid >> 7) * 4;
        float b2j = b2[j];
        float acc2[4];
        #pragma unroll
        for (int m = 0; m < 4; ++m) acc2[m] = b2j;
        for (int k = 0; k < 256; ++k) {
            float wv = W2[k * 128 + j];
            #pragma unroll
            for (int m = 0; m < 4; ++m) acc2[m] += s_y[n0 + m][k] * wv;
        }
        #pragma unroll
        for (int m = 0; m < 4; ++m) {
            size_t g = (size_t)(nb + n0 + m) * HH + j;
            out[g] = h[g] + acc2[m];
        }
    }
}

// ---------------------------------------------------------------------------
extern "C" void kernel_launch(void* const* d_in, const int* in_sizes, int n_in,
                              void* d_out, int out_size, void* d_ws, size_t ws_size,
                              hipStream_t stream)
{
    const float* h   = (const float*)d_in[0];
    const int*   ei  = (const int*)d_in[1];
    const float* ea  = (const float*)d_in[2];
    const float* bnw = (const float*)d_in[3];
    const float* bnb = (const float*)d_in[4];
    const float* bnm = (const float*)d_in[5];
    const float* bnv = (const float*)d_in[6];
    const float* t   = (const float*)d_in[7];
    const float* W1  = (const float*)d_in[8];
    const float* b1  = (const float*)d_in[9];
    const float* lnw = (const float*)d_in[10];
    const float* lnb = (const float*)d_in[11];
    const float* W2  = (const float*)d_in[12];
    const float* b2  = (const float*)d_in[13];
    float* out = (float*)d_out;

    const size_t NH = (size_t)NN * HH;
    float* hn    = (float*)d_ws;
    float* denom = hn + NH;
    // num lives in ws if it fits; else alias d_out (mlp_kernel reads num for a
    // node strictly before writing that node's outputs, same block -> safe).
    float* num   = (ws_size >= 3 * NH * sizeof(float)) ? (denom + NH) : out;

    init_kernel<<<(int)(NH / 1024), 256, 0, stream>>>(h, bnw, bnb, bnm, bnv,
                                                      hn, denom, num);
    edge_kernel<<<EE * 32 / 256, 256, 0, stream>>>(hn, ei, ea, t, denom, num);
    mlp_kernel<<<NN / 8, 256, 0, stream>>>(h, hn, denom, num,
                                           W1, b1, lnw, lnb, W2, b2, out);
}

// Round 4
// 928.088 us; speedup vs baseline: 3.5273x; 3.5273x over previous
//
#include <hip/hip_runtime.h>

#define NN 50000
#define HH 128
#define EE 800000

// ---------------------------------------------------------------------------
// Kernel 1: BN(eval) + ReLU -> hn ; zero deg histogram
// ---------------------------------------------------------------------------
__global__ __launch_bounds__(256) void init_kernel(
    const float* __restrict__ h,
    const float* __restrict__ bnw,
    const float* __restrict__ bnb,
    const float* __restrict__ bnm,
    const float* __restrict__ bnv,
    float* __restrict__ hn,
    int*   __restrict__ deg)
{
    int i4 = blockIdx.x * 256 + threadIdx.x;      // N*H/4 = 1.6M threads exactly
    int c4 = i4 & 31;                              // 128/4 = 32 float4 per row
    const float4 wv = ((const float4*)bnw)[c4];
    const float4 bv = ((const float4*)bnb)[c4];
    const float4 mv = ((const float4*)bnm)[c4];
    const float4 vv = ((const float4*)bnv)[c4];
    const float4 xv = ((const float4*)h)[i4];
    float4 r;
    r.x = fmaxf((xv.x - mv.x) * rsqrtf(vv.x + 1e-5f) * wv.x + bv.x, 0.f);
    r.y = fmaxf((xv.y - mv.y) * rsqrtf(vv.y + 1e-5f) * wv.y + bv.y, 0.f);
    r.z = fmaxf((xv.z - mv.z) * rsqrtf(vv.z + 1e-5f) * wv.z + bv.z, 0.f);
    r.w = fmaxf((xv.w - mv.w) * rsqrtf(vv.w + 1e-5f) * wv.w + bv.w, 0.f);
    ((float4*)hn)[i4] = r;
    if (i4 < NN) deg[i4] = 0;
}

// ---------------------------------------------------------------------------
// Kernel 2: in-degree histogram (int atomics into 200 KB, L2-resident)
// ---------------------------------------------------------------------------
__global__ __launch_bounds__(256) void hist_kernel(
    const int* __restrict__ ei, int* __restrict__ deg)
{
    int e = blockIdx.x * 256 + threadIdx.x;        // E threads exactly
    atomicAdd(&deg[ei[EE + e]], 1);
}

// ---------------------------------------------------------------------------
// Kernel 3: exclusive prefix sum of deg -> rowptr. Single block, 1024 threads.
// ---------------------------------------------------------------------------
__global__ __launch_bounds__(1024) void scan_kernel(
    const int* __restrict__ deg, int* __restrict__ rowptr)
{
    __shared__ int part[1024];
    const int t = threadIdx.x;
    const int CH = 49;                             // 1024*49 >= 50000
    int lo = t * CH, hi = min(lo + CH, NN);
    int s = 0;
    for (int i = lo; i < hi; ++i) s += deg[i];
    part[t] = s;
    __syncthreads();
    for (int off = 1; off < 1024; off <<= 1) {
        int v = (t >= off) ? part[t - off] : 0;
        __syncthreads();
        part[t] += v;
        __syncthreads();
    }
    int run = part[t] - s;                         // exclusive base for this chunk
    for (int i = lo; i < hi; ++i) { rowptr[i] = run; run += deg[i]; }
}

// ---------------------------------------------------------------------------
// Kernel 4: scatter edges into dst-sorted list. rowptr is bumped by atomics
// (ends as rowptr_orig + deg; gather recovers start = rowptr[n] - deg[n]).
// ---------------------------------------------------------------------------
__global__ __launch_bounds__(256) void scatter_kernel(
    const int* __restrict__ ei, int* __restrict__ rowptr,
    int2* __restrict__ pair)
{
    int e = blockIdx.x * 256 + threadIdx.x;        // E threads exactly
    int src = ei[e];
    int dst = ei[EE + e];
    int pos = atomicAdd(&rowptr[dst], 1);
    pair[pos] = make_int2(e, src);
}

// ---------------------------------------------------------------------------
// Kernel 5: per-node softmax aggregation, one wave (64 lanes) per node.
//   msg = relu(hn[src]+ea)+1e-7 ; ex = exp(msg*t) (max-sub dropped: shift-
//   invariant, logits bounded ~12). Registers accumulate num/denom; single
//   write of aggskip = num/denom + hn. No f32 atomics anywhere.
// ---------------------------------------------------------------------------
__global__ __launch_bounds__(256) void gather_kernel(
    const float* __restrict__ hn,
    const float* __restrict__ ea,
    const int*   __restrict__ rowptr,   // post-scatter: end offsets
    const int*   __restrict__ deg,
    const int2*  __restrict__ pair,
    const float* __restrict__ tptr,
    float* __restrict__ aggskip)
{
    const int wave = threadIdx.x >> 6;
    const int lane = threadIdx.x & 63;
    const int n = blockIdx.x * 4 + wave;           // grid*4 = 50000 exactly
    const int end   = rowptr[n];
    const int d     = deg[n];
    const int start = end - d;
    const float t = tptr[0];
    const int c = lane * 2;

    float d0 = 0.f, d1 = 0.f, n0 = 0.f, n1 = 0.f;

    int2 pr_next;
    if (start < end) pr_next = pair[start];
    for (int i = start; i < end; ++i) {
        int2 pr = pr_next;
        if (i + 1 < end) pr_next = pair[i + 1];    // overlap index fetch
        const float2 a  = *(const float2*)(ea + (size_t)pr.x * HH + c);
        const float2 hv = *(const float2*)(hn + (size_t)pr.y * HH + c);
        float m0 = fmaxf(hv.x + a.x, 0.f) + 1e-7f;
        float m1 = fmaxf(hv.y + a.y, 0.f) + 1e-7f;
        float e0 = __expf(m0 * t);
        float e1 = __expf(m1 * t);
        d0 += e0; d1 += e1;
        n0 += m0 * e0; n1 += m1 * e1;
    }

    size_t g = (size_t)n * HH + c;
    const float2 hown = *(const float2*)(hn + g);
    float2 r;
    r.x = n0 / (d0 + 1e-16f) + hown.x;
    r.y = n1 / (d1 + 1e-16f) + hown.y;
    *(float2*)(aggskip + g) = r;
}

// ---------------------------------------------------------------------------
// Kernel 6: MLP. 16 nodes per 256-thread block (halves W1/W2 L2 re-reads vs 8).
//   y = relu(LN(aggskip@W1+b1)) ; out = h + y@W2 + b2
// aggskip is aliased to out: each block reads its 16 rows fully (Phase A)
// before writing them (Phase E) — same block, safe.
// ---------------------------------------------------------------------------
#define SY 272   // s_y stride: 272 mod 32 == 16 -> LN-stat reads 2-way (free)
__global__ __launch_bounds__(256) void mlp_kernel(
    const float* __restrict__ h,
    const float* __restrict__ aggskip,
    const float* __restrict__ W1,
    const float* __restrict__ b1,
    const float* __restrict__ lnw,
    const float* __restrict__ lnb,
    const float* __restrict__ W2,
    const float* __restrict__ b2,
    float* __restrict__ out)
{
    __shared__ float s_out[16][128];
    __shared__ float s_y[16 * SY];
    __shared__ float s_mu[16], s_rs[16];

    const int tid = threadIdx.x;
    const int nb  = blockIdx.x * 16;               // 50000/16 = 3125 blocks

    // Phase A: load aggregated+skip rows
    #pragma unroll
    for (int p = 0; p < 8; ++p) {
        int idx = tid + p * 256;                   // 0..2047
        int n = idx >> 7, k = idx & 127;
        s_out[n][k] = aggskip[(size_t)(nb + n) * HH + k];
    }
    __syncthreads();

    // Phase B: y1[j] = out . W1[:,j] + b1[j]  (thread j owns column j, 16 nodes)
    {
        float bj = b1[tid];
        float acc[16];
        #pragma unroll
        for (int n = 0; n < 16; ++n) acc[n] = bj;
        for (int k = 0; k < 128; ++k) {
            float wv = W1[k * 256 + tid];
            #pragma unroll
            for (int n = 0; n < 16; ++n) acc[n] += s_out[n][k] * wv;
        }
        #pragma unroll
        for (int n = 0; n < 16; ++n) s_y[n * SY + tid] = acc[n];
    }
    __syncthreads();

    // Phase C: LayerNorm stats — 16 groups of 16 lanes, one node each
    {
        int grp = tid >> 4, l16 = tid & 15;
        float s = 0.f, sq = 0.f;
        for (int j = l16; j < 256; j += 16) {
            float v = s_y[grp * SY + j];
            s += v; sq += v * v;
        }
        #pragma unroll
        for (int off = 8; off > 0; off >>= 1) {
            s  += __shfl_down(s,  off, 16);
            sq += __shfl_down(sq, off, 16);
        }
        if (l16 == 0) {
            float mu  = s * (1.f / 256.f);
            float var = sq * (1.f / 256.f) - mu * mu;
            s_mu[grp] = mu;
            s_rs[grp] = rsqrtf(var + 1e-5f);
        }
    }
    __syncthreads();

    // Phase D: apply LN + ReLU
    {
        float lw = lnw[tid], lb = lnb[tid];
        #pragma unroll
        for (int n = 0; n < 16; ++n) {
            float v = (s_y[n * SY + tid] - s_mu[n]) * s_rs[n] * lw + lb;
            s_y[n * SY + tid] = fmaxf(v, 0.f);
        }
    }
    __syncthreads();

    // Phase E: z[j] = y . W2[:,j] + b2[j]; final = h + z
    // threads 0..127 -> nodes 0..7 ; threads 128..255 -> nodes 8..15
    {
        int j  = tid & 127;
        int n0 = (tid >> 7) * 8;
        float b2j = b2[j];
        float acc2[8];
        #pragma unroll
        for (int m = 0; m < 8; ++m) acc2[m] = b2j;
        for (int k = 0; k < 256; ++k) {
            float wv = W2[k * 128 + j];
            #pragma unroll
            for (int m = 0; m < 8; ++m) acc2[m] += s_y[(n0 + m) * SY + k] * wv;
        }
        #pragma unroll
        for (int m = 0; m < 8; ++m) {
            size_t g = (size_t)(nb + n0 + m) * HH + j;
            out[g] = h[g] + acc2[m];
        }
    }
}

// ---------------------------------------------------------------------------
extern "C" void kernel_launch(void* const* d_in, const int* in_sizes, int n_in,
                              void* d_out, int out_size, void* d_ws, size_t ws_size,
                              hipStream_t stream)
{
    const float* h   = (const float*)d_in[0];
    const int*   ei  = (const int*)d_in[1];
    const float* ea  = (const float*)d_in[2];
    const float* bnw = (const float*)d_in[3];
    const float* bnb = (const float*)d_in[4];
    const float* bnm = (const float*)d_in[5];
    const float* bnv = (const float*)d_in[6];
    const float* t   = (const float*)d_in[7];
    const float* W1  = (const float*)d_in[8];
    const float* b1  = (const float*)d_in[9];
    const float* lnw = (const float*)d_in[10];
    const float* lnb = (const float*)d_in[11];
    const float* W2  = (const float*)d_in[12];
    const float* b2  = (const float*)d_in[13];
    float* out = (float*)d_out;

    const size_t NH = (size_t)NN * HH;
    // ws layout (needs ~32.4 MB; round-0 run proved ws >= 51.2 MB):
    char* base = (char*)d_ws;
    float* hn     = (float*)base;                               // 25.6 MB
    int*   deg    = (int*)(base + NH * sizeof(float));          // 200 KB
    int*   rowptr = (int*)(base + NH * sizeof(float) + 200000); // 200 KB
    int2*  pair   = (int2*)(base + NH * sizeof(float) + 400000);// 6.4 MB (8B-aligned)
    float* aggskip = out;   // gather writes, mlp reads-then-writes per block

    init_kernel<<<(int)(NH / 1024), 256, 0, stream>>>(h, bnw, bnb, bnm, bnv, hn, deg);
    hist_kernel<<<EE / 256, 256, 0, stream>>>(ei, deg);
    scan_kernel<<<1, 1024, 0, stream>>>(deg, rowptr);
    scatter_kernel<<<EE / 256, 256, 0, stream>>>(ei, rowptr, pair);
    gather_kernel<<<NN / 4, 256, 0, stream>>>(hn, ea, rowptr, deg, pair, t, aggskip);
    mlp_kernel<<<NN / 16, 256, 0, stream>>>(h, aggskip, W1, b1, lnw, lnb, W2, b2, out);
}

// Round 6
// 813.098 us; speedup vs baseline: 4.0261x; 1.1414x over previous
//
#include <hip/hip_runtime.h>

#define NN 50000
#define HH 128
#define EE 800000

typedef __attribute__((ext_vector_type(8))) short bf16x8;
typedef __attribute__((ext_vector_type(4))) float f32x4;

__device__ __forceinline__ short f2b(float f) {   // f32 -> bf16 RNE
    unsigned u = __float_as_uint(f);
    unsigned r = (u + 0x7fffu + ((u >> 16) & 1u)) >> 16;
    return (short)r;
}

// ---------------------------------------------------------------------------
// Kernel 1: BN(eval) + ReLU -> hn ; zero deg histogram
// ---------------------------------------------------------------------------
__global__ __launch_bounds__(256) void init_kernel(
    const float* __restrict__ h,
    const float* __restrict__ bnw,
    const float* __restrict__ bnb,
    const float* __restrict__ bnm,
    const float* __restrict__ bnv,
    float* __restrict__ hn,
    int*   __restrict__ deg)
{
    int i4 = blockIdx.x * 256 + threadIdx.x;      // N*H/4 = 1.6M threads exactly
    int c4 = i4 & 31;
    const float4 wv = ((const float4*)bnw)[c4];
    const float4 bv = ((const float4*)bnb)[c4];
    const float4 mv = ((const float4*)bnm)[c4];
    const float4 vv = ((const float4*)bnv)[c4];
    const float4 xv = ((const float4*)h)[i4];
    float4 r;
    r.x = fmaxf((xv.x - mv.x) * rsqrtf(vv.x + 1e-5f) * wv.x + bv.x, 0.f);
    r.y = fmaxf((xv.y - mv.y) * rsqrtf(vv.y + 1e-5f) * wv.y + bv.y, 0.f);
    r.z = fmaxf((xv.z - mv.z) * rsqrtf(vv.z + 1e-5f) * wv.z + bv.z, 0.f);
    r.w = fmaxf((xv.w - mv.w) * rsqrtf(vv.w + 1e-5f) * wv.w + bv.w, 0.f);
    ((float4*)hn)[i4] = r;
    if (i4 < NN) deg[i4] = 0;
}

// ---------------------------------------------------------------------------
// Kernel 2: weights -> transposed bf16 (W1T [256][128], W2T [128][256])
// ---------------------------------------------------------------------------
__global__ __launch_bounds__(256) void convert_kernel(
    const float* __restrict__ W1, const float* __restrict__ W2,
    short* __restrict__ W1T, short* __restrict__ W2T)
{
    int id = blockIdx.x * 256 + threadIdx.x;       // 65536 threads
    if (id < 32768) {
        int c = id >> 7, k = id & 127;
        W1T[id] = f2b(W1[k * 256 + c]);
    } else {
        int j = id - 32768;
        int c = j >> 8, k = j & 255;
        W2T[j] = f2b(W2[k * 128 + c]);
    }
}

// ---------------------------------------------------------------------------
// Kernel 3: in-degree histogram (int atomics, L2-resident)
// ---------------------------------------------------------------------------
__global__ __launch_bounds__(256) void hist_kernel(
    const int* __restrict__ ei, int* __restrict__ deg)
{
    int e = blockIdx.x * 256 + threadIdx.x;
    atomicAdd(&deg[ei[EE + e]], 1);
}

// ---------------------------------------------------------------------------
// Kernel 4: exclusive scan of deg -> rowptr. 1024 thr, shfl-based (2 barriers).
// ---------------------------------------------------------------------------
__global__ __launch_bounds__(1024) void scan_kernel(
    const int* __restrict__ deg, int* __restrict__ rowptr)
{
    __shared__ int wsum[16];
    const int t = threadIdx.x;
    const int lane = t & 63, wid = t >> 6;
    const int CH = 49;                             // 1024*49 >= 50000
    int lo = t * CH, hi = min(lo + CH, NN);
    int s = 0;
    for (int i = lo; i < hi; ++i) s += deg[i];
    int val = s;                                   // inclusive wave scan
    #pragma unroll
    for (int off = 1; off < 64; off <<= 1) {
        int u = __shfl_up(val, off, 64);
        if (lane >= off) val += u;
    }
    if (lane == 63) wsum[wid] = val;
    __syncthreads();
    if (t < 16) {
        int v = wsum[t];
        #pragma unroll
        for (int off = 1; off < 16; off <<= 1) {
            int u = __shfl_up(v, off, 16);
            if ((t & 15) >= off) v += u;
        }
        wsum[t] = v;
    }
    __syncthreads();
    int base = (wid > 0 ? wsum[wid - 1] : 0) + (val - s);  // exclusive for thread
    int run = base;
    for (int i = lo; i < hi; ++i) { rowptr[i] = run; run += deg[i]; }
}

// ---------------------------------------------------------------------------
// Kernel 5: scatter edges into dst-sorted list (rowptr bumped to end offsets)
// ---------------------------------------------------------------------------
__global__ __launch_bounds__(256) void scatter_kernel(
    const int* __restrict__ ei, int* __restrict__ rowptr,
    int2* __restrict__ pair)
{
    int e = blockIdx.x * 256 + threadIdx.x;
    int src = ei[e];
    int dst = ei[EE + e];
    int pos = atomicAdd(&rowptr[dst], 1);
    pair[pos] = make_int2(e, src);
}

// ---------------------------------------------------------------------------
// Kernel 6: per-node softmax aggregation. One wave per node; lanes 0-31 take
// even edges, 32-63 odd (float4/lane) -> halves dependent-latency chain.
// Combine halves with shfl_xor(32). No max-subtraction (shift-invariant,
// logits bounded ~12). Writes aggskip = num/denom + hn once.
// ---------------------------------------------------------------------------
__global__ __launch_bounds__(256) void gather_kernel(
    const float* __restrict__ hn,
    const float* __restrict__ ea,
    const int*   __restrict__ rowptr,
    const int*   __restrict__ deg,
    const int2*  __restrict__ pair,
    const float* __restrict__ tptr,
    float* __restrict__ aggskip)
{
    const int wave = threadIdx.x >> 6;
    const int lane = threadIdx.x & 63;
    const int n = blockIdx.x * 4 + wave;           // grid*4 = 50000 exactly
    const int end   = rowptr[n];
    const int start = end - deg[n];
    const float t = tptr[0];
    const int c = (lane & 31) * 4;
    const int epar = lane >> 5;

    float4 dn = make_float4(0.f, 0.f, 0.f, 0.f);
    float4 nm = make_float4(0.f, 0.f, 0.f, 0.f);

    int i = start + epar;
    int2 pr_next;
    if (i < end) pr_next = pair[i];
    for (; i < end; i += 2) {
        int2 pr = pr_next;
        if (i + 2 < end) pr_next = pair[i + 2];
        const float4 a  = *(const float4*)(ea + (size_t)pr.x * HH + c);
        const float4 hv = *(const float4*)(hn + (size_t)pr.y * HH + c);
        float m0 = fmaxf(hv.x + a.x, 0.f) + 1e-7f;
        float m1 = fmaxf(hv.y + a.y, 0.f) + 1e-7f;
        float m2 = fmaxf(hv.z + a.z, 0.f) + 1e-7f;
        float m3 = fmaxf(hv.w + a.w, 0.f) + 1e-7f;
        float e0 = __expf(m0 * t);
        float e1 = __expf(m1 * t);
        float e2 = __expf(m2 * t);
        float e3 = __expf(m3 * t);
        dn.x += e0; dn.y += e1; dn.z += e2; dn.w += e3;
        nm.x += m0 * e0; nm.y += m1 * e1; nm.z += m2 * e2; nm.w += m3 * e3;
    }
    dn.x += __shfl_xor(dn.x, 32); dn.y += __shfl_xor(dn.y, 32);
    dn.z += __shfl_xor(dn.z, 32); dn.w += __shfl_xor(dn.w, 32);
    nm.x += __shfl_xor(nm.x, 32); nm.y += __shfl_xor(nm.y, 32);
    nm.z += __shfl_xor(nm.z, 32); nm.w += __shfl_xor(nm.w, 32);

    if (lane < 32) {
        size_t g = (size_t)n * HH + c;
        const float4 hown = *(const float4*)(hn + g);
        float4 r;
        r.x = nm.x / (dn.x + 1e-16f) + hown.x;
        r.y = nm.y / (dn.y + 1e-16f) + hown.y;
        r.z = nm.z / (dn.z + 1e-16f) + hown.z;
        r.w = nm.w / (dn.w + 1e-16f) + hown.w;
        *(float4*)(aggskip + g) = r;
    }
}

// ---------------------------------------------------------------------------
// Kernel 7: MFMA MLP. 16 nodes / block, 4 waves; each wave owns a 64-col slab
// of GEMM1 (256 cols) and a 32-col slab of GEMM2 (128 cols).
//   GEMM1: y[16][256] = A[16][128] @ W1 ; LN+ReLU in-register ; 
//   GEMM2: z[16][128] = y @ W2 ; out = h + z + b2.
// A and y staged in XOR-swizzled bf16 LDS (byte ^= (row&7)<<4) -> 2-way-free
// ds_read_b128 fragments. C/D layout: col=lane&15, row=(lane>>4)*4+reg (m89).
// aggskip aliases out: block reads its rows (Phase A) before writing them.
// ---------------------------------------------------------------------------
__global__ __launch_bounds__(256) void mlp_kernel(
    const float* __restrict__ h,
    const float* __restrict__ aggskip,
    const short* __restrict__ W1T,     // [256][128] bf16 (col-major W1)
    const float* __restrict__ b1,
    const float* __restrict__ lnw,
    const float* __restrict__ lnb,
    const short* __restrict__ W2T,     // [128][256] bf16 (col-major W2)
    const float* __restrict__ b2,
    float* __restrict__ out)
{
    __shared__ __align__(16) short As[16 * 128];   // 4 KB, swizzled rows of 256B
    __shared__ __align__(16) short Yb[16 * 256];   // 8 KB, swizzled rows of 512B
    __shared__ float pS[4][16], pQ[4][16];
    __shared__ float s_mu[16], s_rs[16];

    const int tid = threadIdx.x;
    const int w   = tid >> 6;
    const int l   = tid & 63;
    const int l15 = l & 15;
    const int lg  = l >> 4;                        // k-group 0..3
    const int nb  = blockIdx.x * 16;               // 3125 blocks

    // Phase A: aggskip rows -> bf16 LDS (swizzled)
    {
        int row  = tid >> 4;
        int colb = (tid & 15) * 8;
        const float4* src = (const float4*)(aggskip + (size_t)(nb + row) * HH + colb);
        float4 v0 = src[0], v1 = src[1];
        bf16x8 pk;
        pk[0] = f2b(v0.x); pk[1] = f2b(v0.y); pk[2] = f2b(v0.z); pk[3] = f2b(v0.w);
        pk[4] = f2b(v1.x); pk[5] = f2b(v1.y); pk[6] = f2b(v1.z); pk[7] = f2b(v1.w);
        int sb = (row * 256 + colb * 2) ^ ((row & 7) << 4);
        *(bf16x8*)((char*)As + sb) = pk;
    }
    __syncthreads();

    // GEMM1: A-frags from LDS, B-frags from W1T (L2), 16 MFMA / wave
    bf16x8 af[4];
    #pragma unroll
    for (int ks = 0; ks < 4; ++ks) {
        int off = (lg * 16 + ks * 64) ^ ((l15 & 7) << 4);
        af[ks] = *(bf16x8*)((char*)As + l15 * 256 + off);
    }
    f32x4 acc[4];
    #pragma unroll
    for (int nt = 0; nt < 4; ++nt) {
        int col = w * 64 + nt * 16 + l15;
        const short* bp = W1T + col * 128 + lg * 8;
        f32x4 a = {0.f, 0.f, 0.f, 0.f};
        #pragma unroll
        for (int ks = 0; ks < 4; ++ks) {
            bf16x8 bfr = *(const bf16x8*)(bp + ks * 32);
            a = __builtin_amdgcn_mfma_f32_16x16x32_bf16(af[ks], bfr, a, 0, 0, 0);
        }
        acc[nt] = a;
    }

    // LN stats in-register: +b1, per-node partials, 16-lane shfl reduce
    float b1c[4];
    #pragma unroll
    for (int nt = 0; nt < 4; ++nt) b1c[nt] = b1[w * 64 + nt * 16 + l15];
    #pragma unroll
    for (int i = 0; i < 4; ++i) {
        float s = 0.f, q = 0.f;
        #pragma unroll
        for (int nt = 0; nt < 4; ++nt) {
            float v = acc[nt][i] + b1c[nt];
            acc[nt][i] = v;
            s += v; q += v * v;
        }
        s += __shfl_xor(s, 1); q += __shfl_xor(q, 1);
        s += __shfl_xor(s, 2); q += __shfl_xor(q, 2);
        s += __shfl_xor(s, 4); q += __shfl_xor(q, 4);
        s += __shfl_xor(s, 8); q += __shfl_xor(q, 8);
        if (l15 == 0) { pS[w][lg * 4 + i] = s; pQ[w][lg * 4 + i] = q; }
    }
    __syncthreads();
    if (tid < 16) {
        float S = pS[0][tid] + pS[1][tid] + pS[2][tid] + pS[3][tid];
        float Q = pQ[0][tid] + pQ[1][tid] + pQ[2][tid] + pQ[3][tid];
        float mu  = S * (1.f / 256.f);
        float var = Q * (1.f / 256.f) - mu * mu;
        s_mu[tid] = mu;
        s_rs[tid] = rsqrtf(var + 1e-5f);
    }
    __syncthreads();

    // LN apply + ReLU -> bf16 LDS (swizzled)
    #pragma unroll
    for (int nt = 0; nt < 4; ++nt) {
        int col = w * 64 + nt * 16 + l15;
        float lw = lnw[col], lb = lnb[col];
        #pragma unroll
        for (int i = 0; i < 4; ++i) {
            int r = lg * 4 + i;
            float v = (acc[nt][i] - s_mu[r]) * s_rs[r] * lw + lb;
            v = fmaxf(v, 0.f);
            int sb = (r * 512 + col * 2) ^ ((r & 7) << 4);
            *(short*)((char*)Yb + sb) = f2b(v);
        }
    }
    __syncthreads();

    // GEMM2: A-frags from Yb, B-frags from W2T, 16 MFMA / wave
    bf16x8 a2[8];
    #pragma unroll
    for (int ks = 0; ks < 8; ++ks) {
        int off = (lg * 16 + ks * 64) ^ ((l15 & 7) << 4);
        a2[ks] = *(bf16x8*)((char*)Yb + l15 * 512 + off);
    }
    f32x4 acc2[2];
    #pragma unroll
    for (int nt = 0; nt < 2; ++nt) {
        int col = w * 32 + nt * 16 + l15;
        const short* bp = W2T + col * 256 + lg * 8;
        f32x4 a = {0.f, 0.f, 0.f, 0.f};
        #pragma unroll
        for (int ks = 0; ks < 8; ++ks) {
            bf16x8 bfr = *(const bf16x8*)(bp + ks * 32);
            a = __builtin_amdgcn_mfma_f32_16x16x32_bf16(a2[ks], bfr, a, 0, 0, 0);
        }
        acc2[nt] = a;
    }

    // Epilogue: out = h + z + b2
    #pragma unroll
    for (int nt = 0; nt < 2; ++nt) {
        int col = w * 32 + nt * 16 + l15;
        float bb = b2[col];
        #pragma unroll
        for (int i = 0; i < 4; ++i) {
            int r = lg * 4 + i;
            size_t g = (size_t)(nb + r) * HH + col;
            out[g] = h[g] + acc2[nt][i] + bb;
        }
    }
}

// ---------------------------------------------------------------------------
extern "C" void kernel_launch(void* const* d_in, const int* in_sizes, int n_in,
                              void* d_out, int out_size, void* d_ws, size_t ws_size,
                              hipStream_t stream)
{
    const float* h   = (const float*)d_in[0];
    const int*   ei  = (const int*)d_in[1];
    const float* ea  = (const float*)d_in[2];
    const float* bnw = (const float*)d_in[3];
    const float* bnb = (const float*)d_in[4];
    const float* bnm = (const float*)d_in[5];
    const float* bnv = (const float*)d_in[6];
    const float* t   = (const float*)d_in[7];
    const float* W1  = (const float*)d_in[8];
    const float* b1  = (const float*)d_in[9];
    const float* lnw = (const float*)d_in[10];
    const float* lnb = (const float*)d_in[11];
    const float* W2  = (const float*)d_in[12];
    const float* b2  = (const float*)d_in[13];
    float* out = (float*)d_out;

    const size_t NH = (size_t)NN * HH;
    // ws layout: hn @0 (25.6MB), deg @NH*4 (200KB), rowptr @+200000 (200KB),
    // pair @+400000 (6.4MB), W1T/W2T after (64KB each). Total ~32.6MB.
    char* base = (char*)d_ws;
    float* hn     = (float*)base;
    int*   deg    = (int*)(base + NH * 4);
    int*   rowptr = (int*)(base + NH * 4 + 200000);
    int2*  pair   = (int2*)(base + NH * 4 + 400000);
    short* W1T = (short*)(base + NH * 4 + 400000 + (size_t)EE * 8);
    short* W2T = W1T + 32768;
    float* aggskip = out;   // gather writes; mlp reads-then-writes per block

    init_kernel<<<(int)(NH / 1024), 256, 0, stream>>>(h, bnw, bnb, bnm, bnv, hn, deg);
    convert_kernel<<<256, 256, 0, stream>>>(W1, W2, W1T, W2T);
    hist_kernel<<<EE / 256, 256, 0, stream>>>(ei, deg);
    scan_kernel<<<1, 1024, 0, stream>>>(deg, rowptr);
    scatter_kernel<<<EE / 256, 256, 0, stream>>>(ei, rowptr, pair);
    gather_kernel<<<NN / 4, 256, 0, stream>>>(hn, ea, rowptr, deg, pair, t, aggskip);
    mlp_kernel<<<NN / 16, 256, 0, stream>>>(h, aggskip, W1T, b1, lnw, lnb, W2T, b2, out);
}